// Round 1
// 14085.086 us; speedup vs baseline: 1.0451x; 1.0451x over previous
//
#include <hip/hip_runtime.h>
#include <stdint.h>

#define HID   2048
#define FEAT  1024
#define BATCH 256
#define TWARM 128
#define TSTEP 128
#define NOUT  129
#define NBLK  192
#define NTHR  512
#define RGBLK 24   // blocks per rg group (16 cell + 8 fc) -- the true sync domain

typedef short    v8s __attribute__((ext_vector_type(8)));
typedef float    v4f __attribute__((ext_vector_type(4)));
typedef uint32_t v4u __attribute__((ext_vector_type(4)));
typedef int32_t  v4i __attribute__((ext_vector_type(4)));

// Device-scope buffer ops (SC[1:0]=2 -> bypass L1/L2, coherent at LLC).
#define AUX_SC1 16
__device__ v4i llvm_amdgcn_raw_buffer_load_i32x4(v4i srsrc, int voffset, int soffset, int aux) __asm("llvm.amdgcn.raw.buffer.load.v4i32");
__device__ void llvm_amdgcn_raw_buffer_store_i32x4(v4i data, v4i srsrc, int voffset, int soffset, int aux) __asm("llvm.amdgcn.raw.buffer.store.v4i32");

__device__ __forceinline__ v4i make_srd(const void* p) {
  union { const void* p; uint32_t w[2]; } c; c.p = p;
  v4i srd;
  srd.x = (int)c.w[0];
  srd.y = (int)c.w[1];
  srd.z = (int)0xFFFFFFFFu;   // disable bounds check
  srd.w = 0x00020000;         // raw untyped dword
  return srd;
}

__device__ __forceinline__ uint32_t bf16_bits(float f) {
  union { float f; uint32_t u; } c; c.f = f;
  return (c.u + 0x8000u) >> 16;
}

__device__ __forceinline__ v4f mfma16(v8s a, v8s b, v4f c) {
  return __builtin_amdgcn_mfma_f32_16x16x32_bf16(a, b, c, 0, 0, 0);
}

// fp32 x8 -> bf16 A-fragment (warmup X path)
__device__ __forceinline__ v8s a_from_f32(const float* p) {
  v4u x0 = *(const v4u*)p;
  v4u x1 = *(const v4u*)(p + 4);
  uint32_t r0 = __builtin_amdgcn_perm(x0.y + 0x8000u, x0.x + 0x8000u, 0x07060302u);
  uint32_t r1 = __builtin_amdgcn_perm(x0.w + 0x8000u, x0.z + 0x8000u, 0x07060302u);
  uint32_t r2 = __builtin_amdgcn_perm(x1.y + 0x8000u, x1.x + 0x8000u, 0x07060302u);
  uint32_t r3 = __builtin_amdgcn_perm(x1.w + 0x8000u, x1.z + 0x8000u, 0x07060302u);
  union { v4u u; v8s s; } c; c.u = (v4u){r0, r1, r2, r3};
  return c.s;
}

// ---------------------------------------------------------------------------
// pack_b: W [N][K] fp32 row-major -> bf16 fragment chunks (1 KB each).
// ---------------------------------------------------------------------------
__global__ void pack_b(const float* __restrict__ W, uint32_t* __restrict__ out,
                       int K, int total_chunks) {
  int gid = blockIdx.x * blockDim.x + threadIdx.x;
  if (gid >= total_chunks) return;
  int lane = gid & 63, tile = gid >> 6;
  int k_tiles = K >> 5;
  int n_tile = tile / k_tiles;
  int k_tile = tile - n_tile * k_tiles;
  const float* src = W + (size_t)(n_tile * 16 + (lane & 15)) * K + k_tile * 32 + ((lane >> 4) * 8);
  uint32_t w0 = bf16_bits(src[0]) | (bf16_bits(src[1]) << 16);
  uint32_t w1 = bf16_bits(src[2]) | (bf16_bits(src[3]) << 16);
  uint32_t w2 = bf16_bits(src[4]) | (bf16_bits(src[5]) << 16);
  uint32_t w3 = bf16_bits(src[6]) | (bf16_bits(src[7]) << 16);
  *(v4u*)(out + (size_t)gid * 4) = (v4u){w0, w1, w2, w3};
}

// pack_bT: chunks of Wfc^T, i.e. B[h][f] = Wfc[f][h]. 128 h_tiles x 32 f_tiles.
__global__ void pack_bT(const float* __restrict__ Wfc, uint16_t* __restrict__ outp) {
  int gid = blockIdx.x * blockDim.x + threadIdx.x;   // chunk*64 + lane
  int lane = gid & 63, tile = gid >> 6;
  int h_tile = tile >> 5, f_tile = tile & 31;
  int f0 = f_tile * 32 + (lane >> 4) * 8;
  int h  = h_tile * 16 + (lane & 15);
  uint16_t* dst = outp + (size_t)tile * 512 + lane * 8;
  #pragma unroll
  for (int j = 0; j < 8; ++j)
    dst[j] = (uint16_t)bf16_bits(Wfc[(size_t)(f0 + j) * HID + h]);
}

// b_comb[n] = b_ih[n] + b_hh[n] + sum_f Wih[n][f] * b_fc[f].  One wave per n.
__global__ void bias_comb_k(const float* __restrict__ Wih, const float* __restrict__ b_ih,
                            const float* __restrict__ b_hh, const float* __restrict__ b_fc,
                            float* __restrict__ b_comb) {
  int wave = threadIdx.x >> 6, lane = threadIdx.x & 63;
  int n = blockIdx.x * 8 + wave;
  const float* wr = Wih + (size_t)n * FEAT;
  float s = 0.f;
  for (int f = lane; f < FEAT; f += 64) s += wr[f] * b_fc[f];
  for (int off = 32; off; off >>= 1) s += __shfl_down(s, off, 64);
  if (lane == 0) b_comb[n] = s + b_ih[n] + b_hh[n];
}

// ---------------------------------------------------------------------------
// comb_gemm: comb[n][h] = Whh[n][h] + sum_f Wih[n][f]*Wfc[f][h]
// ---------------------------------------------------------------------------
__global__ __launch_bounds__(512) void comb_gemm(
    const uint16_t* __restrict__ wih_p, const uint16_t* __restrict__ wfcT_p,
    const float* __restrict__ Whh, uint16_t* __restrict__ comb_p)
{
  __shared__ uint16_t scratch[8][640];
  int wave = threadIdx.x >> 6, lane = threadIdx.x & 63;
  int quad = lane >> 4, l15 = lane & 15;
  int id = blockIdx.x * 8 + wave;     // 0..8191
  int n_tile = id >> 6;               // 0..127
  int k_tile = id & 63;               // h/32
  v4f acc0 = {0.f,0.f,0.f,0.f}, acc1 = {0.f,0.f,0.f,0.f};
  const uint16_t* A  = wih_p  + (size_t)n_tile * 32 * 512 + lane * 8;
  const uint16_t* B0 = wfcT_p + (size_t)(k_tile * 2) * 32 * 512 + lane * 8;
  const uint16_t* B1 = B0 + 32 * 512;
  #pragma unroll 8
  for (int f = 0; f < 32; ++f) {
    v8s a = *(const v8s*)(A + f * 512);
    acc0 = mfma16(a, *(const v8s*)(B0 + f * 512), acc0);
    acc1 = mfma16(a, *(const v8s*)(B1 + f * 512), acc1);
  }
  uint16_t* sc = &scratch[wave][0];
  #pragma unroll
  for (int r = 0; r < 4; ++r) {
    int n = n_tile * 16 + quad * 4 + r;
    int h = k_tile * 32 + l15;
    float v0 = acc0[r] + Whh[(size_t)n * HID + h];
    float v1 = acc1[r] + Whh[(size_t)n * HID + h + 16];
    sc[(quad*4+r)*40 + l15]      = (uint16_t)bf16_bits(v0);
    sc[(quad*4+r)*40 + 16 + l15] = (uint16_t)bf16_bits(v1);
  }
  v4u d = *(v4u*)(sc + l15 * 40 + quad * 8);
  *(v4u*)(comb_p + ((size_t)(n_tile * 64 + k_tile)) * 512 + lane * 8) = d;
}

// ---------------------------------------------------------------------------
// rg-local barrier: the h dataflow is entirely within one rg group (24
// blocks: 16 cell + 8 fc).  Each rg has its own LLC counter (own 128B line).
// Monotone targets, agent-scope atomics -> correct for any XCD placement.
// ---------------------------------------------------------------------------
__device__ __forceinline__ void rg_barrier(uint32_t* bar_rg, uint32_t target) {
  __syncthreads();                       // drains vmcnt/lgkmcnt
  if (threadIdx.x == 0) {
    __hip_atomic_fetch_add(bar_rg, 1u, __ATOMIC_RELAXED, __HIP_MEMORY_SCOPE_AGENT);
    while (__hip_atomic_load(bar_rg, __ATOMIC_RELAXED, __HIP_MEMORY_SCOPE_AGENT) < target) {
      __builtin_amdgcn_s_sleep(1);
    }
  }
  __syncthreads();
}

// ---------------------------------------------------------------------------
// Persistent kernel. 192 blocks x 512 thr. block: cg = bid%24, rg = bid/24.
// XCD = bid%8 = cg%8 -> same-cg blocks share one XCD's L2 for weights.
// h chunk traffic + sync are rg-local (24 blocks).
// Per step: issue ALL 16 h loads (v4i q[16], regs) immediately after the
// barrier, then drain through the 2x16KB LDS double buffer -- one LLC
// latency per step instead of eight.
// ---------------------------------------------------------------------------
__global__ __launch_bounds__(NTHR) void rnn_persistent(
    const float* __restrict__ X,
    const uint16_t* __restrict__ whh_p, const uint16_t* __restrict__ wih_p,
    const uint16_t* __restrict__ wfc_p, const uint16_t* __restrict__ comb_p,
    const float* __restrict__ b_comb, const float* __restrict__ b_fc,
    uint16_t* h0, uint16_t* h1,
    float* __restrict__ out, uint32_t* __restrict__ bar)
{
  __shared__ uint16_t abuf[2][8192];      // 2 x 16 KB A-stage
  __shared__ uint16_t scratch[8][640];    // per-wave D->A transpose bounce

  const int bid  = blockIdx.x;
  const int cg   = bid % 24;
  const int rg   = bid / 24;
  const int tid  = threadIdx.x;
  const int wave = tid >> 6;
  const int lane = tid & 63;
  const int quad = lane >> 4;
  const int l15  = lane & 15;
  const int m_sub = wave & 1;
  const int cpair = wave >> 1;

  const bool is_cell = (cg < 16);
  const int  fcg = cg - 16;
  const int  nt0 = (is_cell ? cg : fcg) * 8 + cpair * 2;

  float bias0, bias1;
  if (is_cell) {
    int c = cg * 128 + cpair * 32 + l15;
    bias0 = b_comb[c]; bias1 = b_comb[c + 16];
  } else {
    int c = fcg * 128 + cpair * 32 + l15;
    bias0 = b_fc[c];   bias1 = b_fc[c + 16];
  }

  const int m_tile     = rg * 2 + m_sub;
  const int k_tile_out = cg * 4 + cpair;         // cell h-chunk this wave writes
  uint16_t* sc = &scratch[wave][0];
  uint32_t* bar_rg = bar + rg * 32;              // per-rg counter, own line

  v4i srd_cur = make_srd(h0);
  v4i srd_nxt = make_srd(h1);

  uint32_t bar_t = 0;
  const int hbase = rg * 131072;                 // this rg's 128KB h slice

  // ---------------- warmup: h' = relu(h@Whh^T + x_t@Wih^T + b_ih + b_hh) ----
  for (int t = 0; t < TWARM; ++t) {
    if (is_cell) {
      v4f acc0 = {0.f,0.f,0.f,0.f}, acc1 = {0.f,0.f,0.f,0.f};
      v4i q[16];
      // issue ALL h loads first: LLC latency hides under the X GEMM below
      if (t > 0) {
        #pragma unroll
        for (int s = 0; s < 8; ++s) {
          q[s]     = llvm_amdgcn_raw_buffer_load_i32x4(srd_cur, hbase + s*8192 + tid*16, 0, AUX_SC1);
          q[s + 8] = llvm_amdgcn_raw_buffer_load_i32x4(srd_cur, hbase + 65536 + s*8192 + tid*16, 0, AUX_SC1);
        }
      }
      // X part, K=1024 (normal cached loads; X is constant)
      {
        const float* xr = X + ((size_t)(rg*32 + m_sub*16 + l15) * TWARM + t) * FEAT + quad*8;
        const uint16_t* wb0 = wih_p + (size_t)nt0 * 32 * 512 + lane*8;
        const uint16_t* wb1 = wb0 + 32*512;
        #pragma unroll 4
        for (int ks = 0; ks < 32; ++ks) {
          v8s a = a_from_f32(xr + ks*32);
          acc0 = mfma16(a, *(const v8s*)(wb0 + ks*512), acc0);
          acc1 = mfma16(a, *(const v8s*)(wb1 + ks*512), acc1);
        }
      }
      // staged K=2048 over h chunks, A fed from regs
      if (t > 0) {
        *(v4i*)(&abuf[0][0]    + tid*8) = q[0];
        *(v4i*)(&abuf[0][4096] + tid*8) = q[8];
        __syncthreads();
        #pragma unroll
        for (int s = 0; s < 8; ++s) {
          const uint16_t* ab = &abuf[s&1][0] + m_sub*4096 + lane*8;
          const uint16_t* b0 = whh_p + ((size_t)nt0*64 + s*8)*512 + lane*8;
          const uint16_t* b1 = b0 + 64*512;
          #pragma unroll
          for (int kt = 0; kt < 8; ++kt) {
            v8s a = *(const v8s*)(ab + kt*512);
            acc0 = mfma16(a, *(const v8s*)(b0 + kt*512), acc0);
            acc1 = mfma16(a, *(const v8s*)(b1 + kt*512), acc1);
          }
          if (s < 7) {
            *(v4i*)(&abuf[(s+1)&1][0]    + tid*8) = q[s+1];
            *(v4i*)(&abuf[(s+1)&1][4096] + tid*8) = q[s+9];
            __syncthreads();
          }
        }
      }
      // relu + bias, transpose to A-chunk, sc1 store
      #pragma unroll
      for (int r = 0; r < 4; ++r) {
        float v0 = acc0[r] + bias0; v0 = v0 > 0.f ? v0 : 0.f;
        float v1 = acc1[r] + bias1; v1 = v1 > 0.f ? v1 : 0.f;
        sc[(quad*4+r)*40 + l15]      = (uint16_t)bf16_bits(v0);
        sc[(quad*4+r)*40 + 16 + l15] = (uint16_t)bf16_bits(v1);
      }
      v4i d = *(v4i*)(sc + l15*40 + quad*8);
      llvm_amdgcn_raw_buffer_store_i32x4(d, srd_nxt,
          ((m_tile*64 + k_tile_out) << 10) + lane*16, 0, AUX_SC1);
    }
    rg_barrier(bar_rg, bar_t += RGBLK);
    v4i tmp = srd_cur; srd_cur = srd_nxt; srd_nxt = tmp;
  }

  // ---------------- AR: h' = relu(h@comb^T + b_comb) (cell blocks)
  // and out_s = h@Wfc^T + b_fc (fc blocks) ---------------------------------
  for (int s_step = 0; s_step <= TSTEP; ++s_step) {
    const bool active = is_cell ? (s_step < TSTEP) : true;
    if (active) {
      const uint16_t* Bbase = is_cell ? comb_p : wfc_p;
      v4f acc0 = {0.f,0.f,0.f,0.f}, acc1 = {0.f,0.f,0.f,0.f};
      v4i q[16];
      #pragma unroll
      for (int s = 0; s < 8; ++s) {
        q[s]     = llvm_amdgcn_raw_buffer_load_i32x4(srd_cur, hbase + s*8192 + tid*16, 0, AUX_SC1);
        q[s + 8] = llvm_amdgcn_raw_buffer_load_i32x4(srd_cur, hbase + 65536 + s*8192 + tid*16, 0, AUX_SC1);
      }
      *(v4i*)(&abuf[0][0]    + tid*8) = q[0];
      *(v4i*)(&abuf[0][4096] + tid*8) = q[8];
      __syncthreads();
      #pragma unroll
      for (int s = 0; s < 8; ++s) {
        const uint16_t* ab = &abuf[s&1][0] + m_sub*4096 + lane*8;
        const uint16_t* b0 = Bbase + ((size_t)nt0*64 + s*8)*512 + lane*8;
        const uint16_t* b1 = b0 + 64*512;
        #pragma unroll
        for (int kt = 0; kt < 8; ++kt) {
          v8s a = *(const v8s*)(ab + kt*512);
          acc0 = mfma16(a, *(const v8s*)(b0 + kt*512), acc0);
          acc1 = mfma16(a, *(const v8s*)(b1 + kt*512), acc1);
        }
        if (s < 7) {
          *(v4i*)(&abuf[(s+1)&1][0]    + tid*8) = q[s+1];
          *(v4i*)(&abuf[(s+1)&1][4096] + tid*8) = q[s+9];
          __syncthreads();
        }
      }
      if (is_cell) {
        #pragma unroll
        for (int r = 0; r < 4; ++r) {
          float v0 = acc0[r] + bias0; v0 = v0 > 0.f ? v0 : 0.f;
          float v1 = acc1[r] + bias1; v1 = v1 > 0.f ? v1 : 0.f;
          sc[(quad*4+r)*40 + l15]      = (uint16_t)bf16_bits(v0);
          sc[(quad*4+r)*40 + 16 + l15] = (uint16_t)bf16_bits(v1);
        }
        v4i d = *(v4i*)(sc + l15*40 + quad*8);
        llvm_amdgcn_raw_buffer_store_i32x4(d, srd_nxt,
            ((m_tile*64 + k_tile_out) << 10) + lane*16, 0, AUX_SC1);
      } else {
        #pragma unroll
        for (int r = 0; r < 4; ++r) {
          int row = rg*32 + m_sub*16 + quad*4 + r;
          float* o = out + ((size_t)row * NOUT + s_step) * FEAT + fcg*128 + cpair*32 + l15;
          o[0]  = acc0[r] + bias0;
          o[16] = acc1[r] + bias1;
        }
      }
    }
    if (s_step < TSTEP) {
      rg_barrier(bar_rg, bar_t += RGBLK);
      v4i tmp = srd_cur; srd_cur = srd_nxt; srd_nxt = tmp;
    }
  }
}

// ---------------------------------------------------------------------------
extern "C" void kernel_launch(void* const* d_in, const int* in_sizes, int n_in,
                              void* d_out, int out_size, void* d_ws, size_t ws_size,
                              hipStream_t stream) {
  const float* X   = (const float*)d_in[0];  // [256][128][1024]
  const float* Wih = (const float*)d_in[1];  // [2048][1024]
  const float* bih = (const float*)d_in[2];
  const float* Whh = (const float*)d_in[3];  // [2048][2048]
  const float* bhh = (const float*)d_in[4];
  const float* Wfc = (const float*)d_in[5];  // [1024][2048]
  const float* bfc = (const float*)d_in[6];
  float* out = (float*)d_out;

  // ws layout (bytes), ~30 MB total
  char* ws = (char*)d_ws;
  uint32_t* bar    = (uint32_t*)(ws + 0);
  uint16_t* h0     = (uint16_t*)(ws + 4096);
  uint16_t* h1     = (uint16_t*)(ws + 4096 + 1048576);
  uint16_t* whh_p  = (uint16_t*)(ws + 2101248);
  uint16_t* wih_p  = (uint16_t*)(ws + 10489856);
  uint16_t* wfc_p  = (uint16_t*)(ws + 14684160);
  uint16_t* wfcT_p = (uint16_t*)(ws + 18878464);
  uint16_t* comb_p = (uint16_t*)(ws + 23072768);
  float*    b_comb = (float*)(ws + 31461376);

  hipMemsetAsync(bar, 0, 4096, stream);

  pack_b<<<(HID*HID/8)/256, 256, 0, stream>>>(Whh, (uint32_t*)whh_p, HID,  HID*HID/8);
  pack_b<<<(HID*FEAT/8)/256, 256, 0, stream>>>(Wih, (uint32_t*)wih_p, FEAT, HID*FEAT/8);
  pack_b<<<(FEAT*HID/8)/256, 256, 0, stream>>>(Wfc, (uint32_t*)wfc_p, HID,  FEAT*HID/8);
  pack_bT<<<(FEAT*HID/8)/256, 256, 0, stream>>>(Wfc, wfcT_p);
  bias_comb_k<<<256, 512, 0, stream>>>(Wih, bih, bhh, bfc, b_comb);
  comb_gemm<<<1024, 512, 0, stream>>>(wih_p, wfcT_p, Whh, comb_p);

  rnn_persistent<<<NBLK, NTHR, 0, stream>>>(X, whh_p, wih_p, wfc_p, comb_p,
                                            b_comb, bfc, h0, h1, out, bar);
}

// Round 3
// 8262.592 us; speedup vs baseline: 1.7815x; 1.7047x over previous
//
#include <hip/hip_runtime.h>
#include <stdint.h>

#define HID   2048
#define FEAT  1024
#define BATCH 256
#define TWARM 128
#define TSTEP 128
#define NOUT  129
#define NBLK  384
#define NTHR  384

typedef short    v8s __attribute__((ext_vector_type(8)));
typedef float    v4f __attribute__((ext_vector_type(4)));
typedef uint32_t v4u __attribute__((ext_vector_type(4)));
typedef int32_t  v4i __attribute__((ext_vector_type(4)));

// Buffer load with CPol aux. aux=1 (sc0): bypass L1, served by L2 -> safe for
// same-XCD producer/consumer h exchange (L2 is the XCD coherence point).
__device__ v4i llvm_amdgcn_raw_buffer_load_i32x4(v4i srsrc, int voffset, int soffset, int aux) __asm("llvm.amdgcn.raw.buffer.load.v4i32");

__device__ __forceinline__ v4i make_srd(const void* p) {
  union { const void* p; uint32_t w[2]; } c; c.p = p;
  v4i srd;
  srd.x = (int)c.w[0];
  srd.y = (int)c.w[1];
  srd.z = (int)0xFFFFFFFFu;   // disable bounds check
  srd.w = 0x00020000;         // raw untyped dword
  return srd;
}

__device__ __forceinline__ uint32_t bf16_bits(float f) {
  union { float f; uint32_t u; } c; c.f = f;
  return (c.u + 0x8000u) >> 16;
}

__device__ __forceinline__ v4f mfma16(v8s a, v8s b, v4f c) {
  return __builtin_amdgcn_mfma_f32_16x16x32_bf16(a, b, c, 0, 0, 0);
}

// fp32 x8 -> bf16 A-fragment (warmup X path)
__device__ __forceinline__ v8s a_from_f32(const float* p) {
  v4u x0 = *(const v4u*)p;
  v4u x1 = *(const v4u*)(p + 4);
  uint32_t r0 = __builtin_amdgcn_perm(x0.y + 0x8000u, x0.x + 0x8000u, 0x07060302u);
  uint32_t r1 = __builtin_amdgcn_perm(x0.w + 0x8000u, x0.z + 0x8000u, 0x07060302u);
  uint32_t r2 = __builtin_amdgcn_perm(x1.y + 0x8000u, x1.x + 0x8000u, 0x07060302u);
  uint32_t r3 = __builtin_amdgcn_perm(x1.w + 0x8000u, x1.z + 0x8000u, 0x07060302u);
  union { v4u u; v8s s; } c; c.u = (v4u){r0, r1, r2, r3};
  return c.s;
}

// ---------------------------------------------------------------------------
// pack_b: W [N][K] fp32 row-major -> bf16 fragment chunks (1 KB each).
// chunk (n_tile, k_tile): lane holds W[n_tile*16+(lane&15)][k_tile*32+(lane>>4)*8+j]
// ---------------------------------------------------------------------------
__global__ void pack_b(const float* __restrict__ W, uint32_t* __restrict__ out,
                       int K, int total_chunks) {
  int gid = blockIdx.x * blockDim.x + threadIdx.x;
  if (gid >= total_chunks) return;
  int lane = gid & 63, tile = gid >> 6;
  int k_tiles = K >> 5;
  int n_tile = tile / k_tiles;
  int k_tile = tile - n_tile * k_tiles;
  const float* src = W + (size_t)(n_tile * 16 + (lane & 15)) * K + k_tile * 32 + ((lane >> 4) * 8);
  uint32_t w0 = bf16_bits(src[0]) | (bf16_bits(src[1]) << 16);
  uint32_t w1 = bf16_bits(src[2]) | (bf16_bits(src[3]) << 16);
  uint32_t w2 = bf16_bits(src[4]) | (bf16_bits(src[5]) << 16);
  uint32_t w3 = bf16_bits(src[6]) | (bf16_bits(src[7]) << 16);
  *(v4u*)(out + (size_t)gid * 4) = (v4u){w0, w1, w2, w3};
}

// pack_bT: chunks of Wfc^T, i.e. B[h][f] = Wfc[f][h]. 128 h_tiles x 32 f_tiles.
__global__ void pack_bT(const float* __restrict__ Wfc, uint16_t* __restrict__ outp) {
  int gid = blockIdx.x * blockDim.x + threadIdx.x;   // chunk*64 + lane
  int lane = gid & 63, tile = gid >> 6;
  int h_tile = tile >> 5, f_tile = tile & 31;
  int f0 = f_tile * 32 + (lane >> 4) * 8;
  int h  = h_tile * 16 + (lane & 15);
  uint16_t* dst = outp + (size_t)tile * 512 + lane * 8;
  #pragma unroll
  for (int j = 0; j < 8; ++j)
    dst[j] = (uint16_t)bf16_bits(Wfc[(size_t)(f0 + j) * HID + h]);
}

// b_comb[n] = b_ih[n] + b_hh[n] + sum_f Wih[n][f] * b_fc[f]  (AR combined bias)
// b_warm[n] = b_ih[n] + b_hh[n]                              (warmup bias)
__global__ void bias_comb_k(const float* __restrict__ Wih, const float* __restrict__ b_ih,
                            const float* __restrict__ b_hh, const float* __restrict__ b_fc,
                            float* __restrict__ b_comb, float* __restrict__ b_warm) {
  int wave = threadIdx.x >> 6, lane = threadIdx.x & 63;
  int n = blockIdx.x * 8 + wave;
  const float* wr = Wih + (size_t)n * FEAT;
  float s = 0.f;
  for (int f = lane; f < FEAT; f += 64) s += wr[f] * b_fc[f];
  for (int off = 32; off; off >>= 1) s += __shfl_down(s, off, 64);
  if (lane == 0) {
    b_comb[n] = s + b_ih[n] + b_hh[n];
    b_warm[n] = b_ih[n] + b_hh[n];
  }
}

// ---------------------------------------------------------------------------
// comb_gemm: comb[n][h] = Whh[n][h] + sum_f Wih[n][f]*Wfc[f][h]
// ---------------------------------------------------------------------------
__global__ __launch_bounds__(512) void comb_gemm(
    const uint16_t* __restrict__ wih_p, const uint16_t* __restrict__ wfcT_p,
    const float* __restrict__ Whh, uint16_t* __restrict__ comb_p)
{
  __shared__ uint16_t scratch[8][640];
  int wave = threadIdx.x >> 6, lane = threadIdx.x & 63;
  int quad = lane >> 4, l15 = lane & 15;
  int id = blockIdx.x * 8 + wave;     // 0..8191
  int n_tile = id >> 6;               // 0..127
  int k_tile = id & 63;               // h/32
  v4f acc0 = {0.f,0.f,0.f,0.f}, acc1 = {0.f,0.f,0.f,0.f};
  const uint16_t* A  = wih_p  + (size_t)n_tile * 32 * 512 + lane * 8;
  const uint16_t* B0 = wfcT_p + (size_t)(k_tile * 2) * 32 * 512 + lane * 8;
  const uint16_t* B1 = B0 + 32 * 512;
  #pragma unroll 8
  for (int f = 0; f < 32; ++f) {
    v8s a = *(const v8s*)(A + f * 512);
    acc0 = mfma16(a, *(const v8s*)(B0 + f * 512), acc0);
    acc1 = mfma16(a, *(const v8s*)(B1 + f * 512), acc1);
  }
  uint16_t* sc = &scratch[wave][0];
  #pragma unroll
  for (int r = 0; r < 4; ++r) {
    int n = n_tile * 16 + quad * 4 + r;
    int h = k_tile * 32 + l15;
    float v0 = acc0[r] + Whh[(size_t)n * HID + h];
    float v1 = acc1[r] + Whh[(size_t)n * HID + h + 16];
    sc[(quad*4+r)*40 + l15]      = (uint16_t)bf16_bits(v0);
    sc[(quad*4+r)*40 + 16 + l15] = (uint16_t)bf16_bits(v1);
  }
  v4u d = *(v4u*)(sc + l15 * 40 + quad * 8);
  *(v4u*)(comb_p + ((size_t)(n_tile * 64 + k_tile)) * 512 + lane * 8) = d;
}

// ---------------------------------------------------------------------------
// Persistent kernel, XCD-local row partitioning with DYNAMIC membership.
// 384 blocks x 384 thr (6 waves). __launch_bounds__(384,3) caps VGPR so 2
// blocks/CU always fit -> capacity 512 > 384 grid -> co-residency has slack.
// Each block reads its physical XCC_ID and claims a per-XCD slot; after one
// global discovery barrier every XCD knows its population Nx (~48) and its
// 64 column-slices (48 cols each over [cell 2048 | fc 1024]) are covered as
// slices {slot, slot+Nx}. Slice1, when present (Nx<64), is provably fc-only
// for Nx>=43. Per-XCD step barrier targets t*Nx -> correct for ANY block->XCD
// distribution. XCD x owns batch rows [32x,32x+32): h never leaves the XCD
// (plain stores -> L2; sc0 loads bypass L1). Weights stream from LLC.
// ---------------------------------------------------------------------------
__global__ __launch_bounds__(NTHR, 3) void rnn_persistent(
    const float* __restrict__ X,
    const uint16_t* __restrict__ whh_p, const uint16_t* __restrict__ wih_p,
    const uint16_t* __restrict__ wfc_p, const uint16_t* __restrict__ comb_p,
    const float* __restrict__ b_comb, const float* __restrict__ b_warm,
    const float* __restrict__ b_fc,
    uint16_t* h0, uint16_t* h1,
    float* __restrict__ out, uint32_t* __restrict__ bar)
{
  __shared__ __align__(16) uint16_t abuf[2][8192];   // 2 x 16 KB A-stage
  __shared__ __align__(16) uint16_t scratch[6][384]; // per-wave D->A transpose bounce
  __shared__ int s_slot, s_nx;

  const int tid  = threadIdx.x;
  const int wave = tid >> 6;
  const int lane = tid & 63;
  const int quad = lane >> 4;
  const int l15  = lane & 15;
  const int m_sub = wave & 1;
  const int ct    = wave >> 1;      // 0..2

  int xcd;
  asm volatile("s_getreg_b32 %0, hwreg(HW_REG_XCC_ID)" : "=s"(xcd));
  xcd &= 7;
  uint32_t* xline = bar + 64 * (1 + xcd);   // 256B-spaced per-XCD line

  // ---- discovery: claim slot on my XCD, then one global barrier ----------
  if (tid == 0) {
    int slot = (int)__hip_atomic_fetch_add(&xline[0], 1u,
                                           __ATOMIC_RELAXED, __HIP_MEMORY_SCOPE_AGENT);
    uint32_t o = __hip_atomic_fetch_add(&bar[0], 1u,
                                        __ATOMIC_RELAXED, __HIP_MEMORY_SCOPE_AGENT);
    if (o == NBLK - 1)
      __hip_atomic_store(&bar[1], 1u, __ATOMIC_RELAXED, __HIP_MEMORY_SCOPE_AGENT);
    while (__hip_atomic_load(&bar[1], __ATOMIC_RELAXED, __HIP_MEMORY_SCOPE_AGENT) == 0)
      __builtin_amdgcn_s_sleep(2);
    s_slot = slot;
    s_nx = (int)__hip_atomic_load(&xline[0], __ATOMIC_RELAXED, __HIP_MEMORY_SCOPE_AGENT);
  }
  __syncthreads();
  const int slot = s_slot;
  const int Nx   = s_nx;            // blocks on this XCD (<= 64 by residency)

  // ---- work assignment: slices slot and slot+Nx (if < 64) ----------------
  const int  sl0   = slot;
  const bool has0  = sl0 < 64;
  const int  g0r   = sl0 * 3 + ct;
  const bool cell0 = has0 && (g0r < 128);
  const bool fc0   = has0 && !cell0;
  const int  sl1   = slot + Nx;
  const int  g1r   = sl1 * 3 + ct;
  const bool has1  = (sl1 < 64) && (g1r >= 128);   // slice1 is fc-only
  const bool has_cellblk = has0 && (sl0 * 3 < 128);
  const bool has_fcblk   = has1 || (has0 && (sl0 * 3 + 2 >= 128));

  const int gc0 = cell0 ? g0r : 0;
  const int gf0 = fc0   ? (g0r - 128) : 0;
  const int gf1 = has1  ? (g1r - 128) : 0;

  float bias_w = 0.f, bias_a = 0.f, bias_f0 = 0.f, bias_f1 = 0.f;
  if (cell0) { bias_w = b_warm[gc0 * 16 + l15]; bias_a = b_comb[gc0 * 16 + l15]; }
  if (fc0)   { bias_f0 = b_fc[gf0 * 16 + l15]; }
  if (has1)  { bias_f1 = b_fc[gf1 * 16 + l15]; }

  const uint16_t* bw_whh = whh_p + (size_t)gc0 * 64 * 512 + lane * 8;
  const uint16_t* bw_cmb = comb_p + (size_t)gc0 * 64 * 512 + lane * 8;
  const uint16_t* bw_fc0 = wfc_p + (size_t)gf0 * 64 * 512 + lane * 8;
  const uint16_t* bw_fc1 = wfc_p + (size_t)gf1 * 64 * 512 + lane * 8;
  const uint16_t* wx     = wih_p + (size_t)gc0 * 32 * 512 + lane * 8;
  const float*    xrow   = X + (size_t)(xcd * 32 + m_sub * 16 + l15) * TWARM * FEAT + quad * 8;
  const int m_tile = xcd * 2 + m_sub;

  v4i srd_cur = make_srd(h0);
  v4i srd_nxt = make_srd(h1);
  uint16_t* hn = h1;

  v4i p0, p1, p2;
  auto stage_issue = [&](int s) {
    int b0 = ((xcd * 128 + 8 * s) << 10);     // m_tile = xcd*2 run, 8 chunks
    int b1 = b0 + (64 << 10);                 // m_tile = xcd*2+1 run
    p0 = llvm_amdgcn_raw_buffer_load_i32x4(srd_cur, b0 + tid * 16, 0, 1);
    int i1 = tid + 384;
    p1 = llvm_amdgcn_raw_buffer_load_i32x4(
        srd_cur, (i1 < 512) ? (b0 + i1 * 16) : (b1 + (i1 - 512) * 16), 0, 1);
    if (tid < 256)
      p2 = llvm_amdgcn_raw_buffer_load_i32x4(srd_cur, b1 + (tid + 256) * 16, 0, 1);
  };
  auto stage_write = [&](int bsel) {
    *(v4i*)(&abuf[bsel][0] + tid * 8) = p0;
    *(v4i*)(&abuf[bsel][0] + (tid + 384) * 8) = p1;
    if (tid < 256) *(v4i*)(&abuf[bsel][0] + (tid + 768) * 8) = p2;
  };

  #pragma unroll 1
  for (int t = 0; t <= TWARM + TSTEP; ++t) {
    const bool warm = t < TWARM;
    const bool doh  = t > 0;
    const bool m0 = doh && (cell0 ? (t < TWARM + TSTEP) : (fc0 && t >= TWARM));
    const bool m1 = has1 && (t >= TWARM);
    const bool any_now = doh && ((has_cellblk && t < TWARM + TSTEP) ||
                                 (has_fcblk && t >= TWARM));

    v4f acc0 = {0.f, 0.f, 0.f, 0.f};
    v4f acc1 = {0.f, 0.f, 0.f, 0.f};

    if (any_now) stage_issue(0);

    // X part (warmup cells): overlaps the stage-0 h-load L2 latency
    if (warm && cell0) {
      const float* xr = xrow + (size_t)t * FEAT;
      #pragma unroll 4
      for (int ks = 0; ks < 32; ++ks)
        acc0 = mfma16(a_from_f32(xr + ks * 32), *(const v8s*)(wx + (size_t)ks * 512), acc0);
    }

    if (any_now) {
      stage_write(0);
      __syncthreads();
      const uint16_t* bb0base = cell0 ? (warm ? bw_whh : bw_cmb) : bw_fc0;
      #pragma unroll 1
      for (int s8 = 0; s8 < 8; ++s8) {
        if (s8 < 7) stage_issue(s8 + 1);
        const uint16_t* ab = &abuf[s8 & 1][m_sub * 4096] + lane * 8;
        const uint16_t* bb0 = bb0base + (size_t)(8 * s8) * 512;
        const uint16_t* bb1 = bw_fc1 + (size_t)(8 * s8) * 512;
        if (m0 && m1) {
          #pragma unroll
          for (int kt = 0; kt < 8; ++kt) {
            v8s a = *(const v8s*)(ab + kt * 512);
            acc0 = mfma16(a, *(const v8s*)(bb0 + kt * 512), acc0);
            acc1 = mfma16(a, *(const v8s*)(bb1 + kt * 512), acc1);
          }
        } else if (m0) {
          #pragma unroll
          for (int kt = 0; kt < 8; ++kt)
            acc0 = mfma16(*(const v8s*)(ab + kt * 512), *(const v8s*)(bb0 + kt * 512), acc0);
        } else if (m1) {
          #pragma unroll
          for (int kt = 0; kt < 8; ++kt)
            acc1 = mfma16(*(const v8s*)(ab + kt * 512), *(const v8s*)(bb1 + kt * 512), acc1);
        }
        if (s8 < 7) stage_write((s8 + 1) & 1);
        __syncthreads();
      }
    }

    // epilogue slice0
    if (cell0 && t < TWARM + TSTEP) {
      float b = warm ? bias_w : bias_a;
      uint16_t* scw = &scratch[wave][0];
      #pragma unroll
      for (int r = 0; r < 4; ++r) {
        float v = acc0[r] + b; v = v > 0.f ? v : 0.f;
        scw[(quad * 4 + r) * 24 + l15] = (uint16_t)bf16_bits(v);
      }
      if (lane < 32) {
        v4u d = *(const v4u*)(scw + l15 * 24 + (lane >> 4) * 8);
        *(v4u*)((char*)hn + ((m_tile * 64 + (gc0 >> 1)) << 10) + (gc0 & 1) * 512 + lane * 16) = d;
      }
    } else if (fc0 && t >= TWARM) {
      int s = t - TWARM;
      #pragma unroll
      for (int r = 0; r < 4; ++r) {
        int row = xcd * 32 + m_sub * 16 + quad * 4 + r;
        out[((size_t)row * NOUT + s) * FEAT + gf0 * 16 + l15] = acc0[r] + bias_f0;
      }
    }
    // epilogue slice1 (fc)
    if (m1) {
      int s = t - TWARM;
      #pragma unroll
      for (int r = 0; r < 4; ++r) {
        int row = xcd * 32 + m_sub * 16 + quad * 4 + r;
        out[((size_t)row * NOUT + s) * FEAT + gf1 * 16 + l15] = acc1[r] + bias_f1;
      }
    }

    if (t < TWARM + TSTEP) {
      // per-XCD step barrier: Nx arrivals, release value t+1
      __syncthreads();                 // drains vmcnt: h stores reached L2
      if (tid == 0) {
        uint32_t o = __hip_atomic_fetch_add(&xline[2], 1u,
                                            __ATOMIC_RELAXED, __HIP_MEMORY_SCOPE_AGENT);
        if (o == (uint32_t)((t + 1) * Nx - 1))
          __hip_atomic_store(&xline[3], (uint32_t)(t + 1),
                             __ATOMIC_RELAXED, __HIP_MEMORY_SCOPE_AGENT);
        while (__hip_atomic_load(&xline[3], __ATOMIC_RELAXED,
                                 __HIP_MEMORY_SCOPE_AGENT) < (uint32_t)(t + 1))
          __builtin_amdgcn_s_sleep(2);
      }
      __syncthreads();
      v4i ts = srd_cur; srd_cur = srd_nxt; srd_nxt = ts;
      hn = (hn == h1) ? h0 : h1;
    }
  }
}

// ---------------------------------------------------------------------------
extern "C" void kernel_launch(void* const* d_in, const int* in_sizes, int n_in,
                              void* d_out, int out_size, void* d_ws, size_t ws_size,
                              hipStream_t stream) {
  const float* X   = (const float*)d_in[0];  // [256][128][1024]
  const float* Wih = (const float*)d_in[1];  // [2048][1024]
  const float* bih = (const float*)d_in[2];
  const float* bhh = (const float*)d_in[4];
  const float* Whh = (const float*)d_in[3];  // [2048][2048]
  const float* Wfc = (const float*)d_in[5];  // [1024][2048]
  const float* bfc = (const float*)d_in[6];
  float* out = (float*)d_out;

  // ws layout (bytes), ~30 MB total (same footprint as the passing rounds)
  char* ws = (char*)d_ws;
  uint32_t* bar    = (uint32_t*)(ws + 0);          // 4096 B barrier/claim lines
  uint16_t* h0     = (uint16_t*)(ws + 4096);
  uint16_t* h1     = (uint16_t*)(ws + 4096 + 1048576);
  uint16_t* whh_p  = (uint16_t*)(ws + 2101248);
  uint16_t* wih_p  = (uint16_t*)(ws + 10489856);
  uint16_t* wfc_p  = (uint16_t*)(ws + 14684160);
  uint16_t* wfcT_p = (uint16_t*)(ws + 18878464);
  uint16_t* comb_p = (uint16_t*)(ws + 23072768);
  float*    b_comb = (float*)(ws + 31461376);
  float*    b_warm = (float*)(ws + 31469568);

  hipMemsetAsync(bar, 0, 4096, stream);

  pack_b<<<(HID*HID/8)/256, 256, 0, stream>>>(Whh, (uint32_t*)whh_p, HID,  HID*HID/8);
  pack_b<<<(HID*FEAT/8)/256, 256, 0, stream>>>(Wih, (uint32_t*)wih_p, FEAT, HID*FEAT/8);
  pack_b<<<(FEAT*HID/8)/256, 256, 0, stream>>>(Wfc, (uint32_t*)wfc_p, HID,  FEAT*HID/8);
  pack_bT<<<(FEAT*HID/8)/256, 256, 0, stream>>>(Wfc, wfcT_p);
  bias_comb_k<<<256, 512, 0, stream>>>(Wih, bih, bhh, bfc, b_comb, b_warm);
  comb_gemm<<<1024, 512, 0, stream>>>(wih_p, wfcT_p, Whh, comb_p);

  rnn_persistent<<<NBLK, NTHR, 0, stream>>>(X, whh_p, wih_p, wfc_p, comb_p,
                                            b_comb, b_warm, bfc, h0, h1, out, bar);
}

// Round 6
// 8078.558 us; speedup vs baseline: 1.8221x; 1.0228x over previous
//
#include <hip/hip_runtime.h>
#include <stdint.h>

#define HID   2048
#define FEAT  1024
#define BATCH 256
#define TWARM 128
#define TSTEP 128
#define NOUT  129
#define NBLK  384
#define NTHR  256

typedef short    v8s __attribute__((ext_vector_type(8)));
typedef float    v4f __attribute__((ext_vector_type(4)));
typedef uint32_t v4u __attribute__((ext_vector_type(4)));
typedef int32_t  v4i __attribute__((ext_vector_type(4)));

// Buffer load with CPol aux. aux=1 (sc0): bypass L1, served by L2 -> safe for
// same-XCD producer/consumer h exchange (L2 is the XCD coherence point).
__device__ v4i llvm_amdgcn_raw_buffer_load_i32x4(v4i srsrc, int voffset, int soffset, int aux) __asm("llvm.amdgcn.raw.buffer.load.v4i32");

__device__ __forceinline__ v4i make_srd(const void* p) {
  union { const void* p; uint32_t w[2]; } c; c.p = p;
  v4i srd;
  srd.x = (int)c.w[0];
  srd.y = (int)c.w[1];
  srd.z = (int)0xFFFFFFFFu;   // disable bounds check
  srd.w = 0x00020000;         // raw untyped dword
  return srd;
}

__device__ __forceinline__ uint32_t bf16_bits(float f) {
  union { float f; uint32_t u; } c; c.f = f;
  return (c.u + 0x8000u) >> 16;
}

__device__ __forceinline__ v4f mfma16(v8s a, v8s b, v4f c) {
  return __builtin_amdgcn_mfma_f32_16x16x32_bf16(a, b, c, 0, 0, 0);
}

// fp32 x8 -> bf16 A-fragment (warmup X path)
__device__ __forceinline__ v8s a_from_f32(const float* p) {
  v4u x0 = *(const v4u*)p;
  v4u x1 = *(const v4u*)(p + 4);
  uint32_t r0 = __builtin_amdgcn_perm(x0.y + 0x8000u, x0.x + 0x8000u, 0x07060302u);
  uint32_t r1 = __builtin_amdgcn_perm(x0.w + 0x8000u, x0.z + 0x8000u, 0x07060302u);
  uint32_t r2 = __builtin_amdgcn_perm(x1.y + 0x8000u, x1.x + 0x8000u, 0x07060302u);
  uint32_t r3 = __builtin_amdgcn_perm(x1.w + 0x8000u, x1.z + 0x8000u, 0x07060302u);
  union { v4u u; v8s s; } c; c.u = (v4u){r0, r1, r2, r3};
  return c.s;
}

// ---------------------------------------------------------------------------
// pack_b: W [N][K] fp32 row-major -> bf16 fragment chunks (1 KB each).
// chunk (n_tile, k_tile): lane holds W[n_tile*16+(lane&15)][k_tile*32+(lane>>4)*8+j]
// ---------------------------------------------------------------------------
__global__ void pack_b(const float* __restrict__ W, uint32_t* __restrict__ out,
                       int K, int total_chunks) {
  int gid = blockIdx.x * blockDim.x + threadIdx.x;
  if (gid >= total_chunks) return;
  int lane = gid & 63, tile = gid >> 6;
  int k_tiles = K >> 5;
  int n_tile = tile / k_tiles;
  int k_tile = tile - n_tile * k_tiles;
  const float* src = W + (size_t)(n_tile * 16 + (lane & 15)) * K + k_tile * 32 + ((lane >> 4) * 8);
  uint32_t w0 = bf16_bits(src[0]) | (bf16_bits(src[1]) << 16);
  uint32_t w1 = bf16_bits(src[2]) | (bf16_bits(src[3]) << 16);
  uint32_t w2 = bf16_bits(src[4]) | (bf16_bits(src[5]) << 16);
  uint32_t w3 = bf16_bits(src[6]) | (bf16_bits(src[7]) << 16);
  *(v4u*)(out + (size_t)gid * 4) = (v4u){w0, w1, w2, w3};
}

// pack_bT: chunks of Wfc^T, i.e. B[h][f] = Wfc[f][h]. 128 h_tiles x 32 f_tiles.
__global__ void pack_bT(const float* __restrict__ Wfc, uint16_t* __restrict__ outp) {
  int gid = blockIdx.x * blockDim.x + threadIdx.x;   // chunk*64 + lane
  int lane = gid & 63, tile = gid >> 6;
  int h_tile = tile >> 5, f_tile = tile & 31;
  int f0 = f_tile * 32 + (lane >> 4) * 8;
  int h  = h_tile * 16 + (lane & 15);
  uint16_t* dst = outp + (size_t)tile * 512 + lane * 8;
  #pragma unroll
  for (int j = 0; j < 8; ++j)
    dst[j] = (uint16_t)bf16_bits(Wfc[(size_t)(f0 + j) * HID + h]);
}

// b_comb[n] = b_ih[n] + b_hh[n] + sum_f Wih[n][f] * b_fc[f]  (AR combined bias)
// b_warm[n] = b_ih[n] + b_hh[n]                              (warmup bias)
__global__ void bias_comb_k(const float* __restrict__ Wih, const float* __restrict__ b_ih,
                            const float* __restrict__ b_hh, const float* __restrict__ b_fc,
                            float* __restrict__ b_comb, float* __restrict__ b_warm) {
  int wave = threadIdx.x >> 6, lane = threadIdx.x & 63;
  int n = blockIdx.x * 8 + wave;
  const float* wr = Wih + (size_t)n * FEAT;
  float s = 0.f;
  for (int f = lane; f < FEAT; f += 64) s += wr[f] * b_fc[f];
  for (int off = 32; off; off >>= 1) s += __shfl_down(s, off, 64);
  if (lane == 0) {
    b_comb[n] = s + b_ih[n] + b_hh[n];
    b_warm[n] = b_ih[n] + b_hh[n];
  }
}

// ---------------------------------------------------------------------------
// comb_gemm: comb[n][h] = Whh[n][h] + sum_f Wih[n][f]*Wfc[f][h]
// ---------------------------------------------------------------------------
__global__ __launch_bounds__(512) void comb_gemm(
    const uint16_t* __restrict__ wih_p, const uint16_t* __restrict__ wfcT_p,
    const float* __restrict__ Whh, uint16_t* __restrict__ comb_p)
{
  __shared__ uint16_t scratch[8][640];
  int wave = threadIdx.x >> 6, lane = threadIdx.x & 63;
  int quad = lane >> 4, l15 = lane & 15;
  int id = blockIdx.x * 8 + wave;     // 0..8191
  int n_tile = id >> 6;               // 0..127
  int k_tile = id & 63;               // h/32
  v4f acc0 = {0.f,0.f,0.f,0.f}, acc1 = {0.f,0.f,0.f,0.f};
  const uint16_t* A  = wih_p  + (size_t)n_tile * 32 * 512 + lane * 8;
  const uint16_t* B0 = wfcT_p + (size_t)(k_tile * 2) * 32 * 512 + lane * 8;
  const uint16_t* B1 = B0 + 32 * 512;
  #pragma unroll 8
  for (int f = 0; f < 32; ++f) {
    v8s a = *(const v8s*)(A + f * 512);
    acc0 = mfma16(a, *(const v8s*)(B0 + f * 512), acc0);
    acc1 = mfma16(a, *(const v8s*)(B1 + f * 512), acc1);
  }
  uint16_t* sc = &scratch[wave][0];
  #pragma unroll
  for (int r = 0; r < 4; ++r) {
    int n = n_tile * 16 + quad * 4 + r;
    int h = k_tile * 32 + l15;
    float v0 = acc0[r] + Whh[(size_t)n * HID + h];
    float v1 = acc1[r] + Whh[(size_t)n * HID + h + 16];
    sc[(quad*4+r)*40 + l15]      = (uint16_t)bf16_bits(v0);
    sc[(quad*4+r)*40 + 16 + l15] = (uint16_t)bf16_bits(v1);
  }
  v4u d = *(v4u*)(sc + l15 * 40 + quad * 8);
  *(v4u*)(comb_p + ((size_t)(n_tile * 64 + k_tile)) * 512 + lane * 8) = d;
}

// ---------------------------------------------------------------------------
// Persistent kernel, XCD-local row partitioning, BARRIER-FREE step body.
//
// 384 blocks x 256 thr (4 waves). launch_bounds(256,2): VGPR cap 256 (no
// spill risk); 2 blocks/CU capacity = 512 > 384 grid (residency slack).
// Discovery + per-XCD step barrier: Round-3 protocol VERBATIM (proven).
//
// Work: per XCD, 192 col-tiles (16 cols each; tiles 0..127 cell, 128..191 fc).
// Wave (slot, w) covers tiles g = w*Nx + slot, g += 4*Nx (unique full cover
// for ANY Nx; exactly one tile per wave when Nx=48). Each wave computes BOTH
// m-tiles (32 rows) for its tile: 128 MFMAs, K=2048.
// A-fragments are read DIRECTLY from the h buffer in L2 via sc0 buffer loads
// (no LDS staging, no intra-step __syncthreads -> no vmcnt(0) drains: the
// compiler pipelines the whole K=2048 load stream, MLP limited only by
// vmcnt depth). Weights stream via plain cached loads.
// ---------------------------------------------------------------------------
__global__ __launch_bounds__(NTHR, 2) void rnn_persistent(
    const float* __restrict__ X,
    const uint16_t* __restrict__ whh_p, const uint16_t* __restrict__ wih_p,
    const uint16_t* __restrict__ wfc_p, const uint16_t* __restrict__ comb_p,
    const float* __restrict__ b_comb, const float* __restrict__ b_warm,
    const float* __restrict__ b_fc,
    uint16_t* h0, uint16_t* h1,
    float* __restrict__ out, uint32_t* __restrict__ bar)
{
  __shared__ __align__(16) uint16_t scratch[4][384]; // per-wave D->A transpose bounce
  __shared__ int s_slot, s_nx;

  const int tid  = threadIdx.x;
  const int wave = tid >> 6;
  const int lane = tid & 63;
  const int quad = lane >> 4;
  const int l15  = lane & 15;

  int xcd;
  asm volatile("s_getreg_b32 %0, hwreg(HW_REG_XCC_ID)" : "=s"(xcd));
  xcd &= 7;
  uint32_t* xline = bar + 64 * (1 + xcd);   // 256B-spaced per-XCD line

  // ---- discovery: claim slot on my XCD, then one global barrier ----------
  if (tid == 0) {
    int slot = (int)__hip_atomic_fetch_add(&xline[0], 1u,
                                           __ATOMIC_RELAXED, __HIP_MEMORY_SCOPE_AGENT);
    uint32_t o = __hip_atomic_fetch_add(&bar[1016], 1u,
                                        __ATOMIC_RELAXED, __HIP_MEMORY_SCOPE_AGENT);
    if (o == NBLK - 1)
      __hip_atomic_store(&bar[1017], 1u, __ATOMIC_RELAXED, __HIP_MEMORY_SCOPE_AGENT);
    while (__hip_atomic_load(&bar[1017], __ATOMIC_RELAXED, __HIP_MEMORY_SCOPE_AGENT) == 0)
      __builtin_amdgcn_s_sleep(2);
    s_slot = slot;
    s_nx = (int)__hip_atomic_load(&xline[0], __ATOMIC_RELAXED, __HIP_MEMORY_SCOPE_AGENT);
  }
  __syncthreads();
  const int slot = s_slot;
  const int Nx   = s_nx;            // blocks on this XCD

  // A-fragment chunk bases for this XCD's two m-tiles (chunk = m_tile*64+k)
  const int a0_off = (((xcd * 2) * 64) << 10) + lane * 16;
  const int a1_off = a0_off + (64 << 10);
  const int row0   = xcd * 32;

  v4i srd_cur = make_srd(h0), srd_nxt = make_srd(h1);
  uint16_t* hw = h1;                 // write target (next h)

  #pragma unroll 1
  for (int t = 0; t <= TWARM + TSTEP; ++t) {
    const bool warm = t < TWARM;

    #pragma unroll 1
    for (int g = wave * Nx + slot; g < 192; g += 4 * Nx) {
      const bool is_cell = g < 128;
      if (is_cell ? (t >= TWARM + TSTEP) : warm) continue;

      v4f acc0 = {0.f, 0.f, 0.f, 0.f};
      v4f acc1 = {0.f, 0.f, 0.f, 0.f};

      // X part (warmup cells), both m-tiles
      if (warm && is_cell) {
        const uint16_t* wx = wih_p + (size_t)g * 32 * 512 + lane * 8;
        const float* xr0 = X + ((size_t)(row0 + l15) * TWARM + t) * FEAT + quad * 8;
        const float* xr1 = xr0 + (size_t)16 * TWARM * FEAT;
        #pragma unroll 4
        for (int ks = 0; ks < 32; ++ks) {
          v8s wv = *(const v8s*)(wx + (size_t)ks * 512);
          acc0 = mfma16(a_from_f32(xr0 + ks * 32), wv, acc0);
          acc1 = mfma16(a_from_f32(xr1 + ks * 32), wv, acc1);
        }
      }

      // h part: K=2048, A streamed from L2 (sc0), W streamed cached
      if (t > 0) {
        const uint16_t* bw = is_cell
            ? (warm ? whh_p : comb_p) + (size_t)g * 64 * 512 + lane * 8
            : wfc_p + (size_t)(g - 128) * 64 * 512 + lane * 8;
        #pragma unroll 8
        for (int k = 0; k < 64; ++k) {
          union { v4i i; v8s s; } ca, cb;
          ca.i = llvm_amdgcn_raw_buffer_load_i32x4(srd_cur, a0_off + k * 1024, 0, 1);
          cb.i = llvm_amdgcn_raw_buffer_load_i32x4(srd_cur, a1_off + k * 1024, 0, 1);
          v8s wv = *(const v8s*)(bw + (size_t)k * 512);
          acc0 = mfma16(ca.s, wv, acc0);
          acc1 = mfma16(cb.s, wv, acc1);
        }
      }

      if (is_cell) {
        const float b = (warm ? b_warm : b_comb)[g * 16 + l15];
        uint16_t* scw = &scratch[wave][0];
        // m-tile 0: relu+bias, transpose to A-chunk layout, store to h(t+1)
        #pragma unroll
        for (int r = 0; r < 4; ++r) {
          float v = acc0[r] + b; v = v > 0.f ? v : 0.f;
          scw[(quad * 4 + r) * 24 + l15] = (uint16_t)bf16_bits(v);
        }
        if (lane < 32) {
          v4u d = *(const v4u*)(scw + l15 * 24 + (lane >> 4) * 8);
          *(v4u*)((char*)hw + ((((xcd * 2) * 64) + (g >> 1)) << 10) + (g & 1) * 512 + lane * 16) = d;
        }
        // m-tile 1 (in-wave scratch reuse; compiler orders same-address LDS ops)
        #pragma unroll
        for (int r = 0; r < 4; ++r) {
          float v = acc1[r] + b; v = v > 0.f ? v : 0.f;
          scw[(quad * 4 + r) * 24 + l15] = (uint16_t)bf16_bits(v);
        }
        if (lane < 32) {
          v4u d = *(const v4u*)(scw + l15 * 24 + (lane >> 4) * 8);
          *(v4u*)((char*)hw + ((((xcd * 2 + 1) * 64) + (g >> 1)) << 10) + (g & 1) * 512 + lane * 16) = d;
        }
      } else {
        const int s = t - TWARM;
        const int f0 = (g - 128) * 16 + l15;
        const float b = b_fc[f0];
        #pragma unroll
        for (int r = 0; r < 4; ++r) {
          out[((size_t)(row0 + quad * 4 + r) * NOUT + s) * FEAT + f0]      = acc0[r] + b;
          out[((size_t)(row0 + 16 + quad * 4 + r) * NOUT + s) * FEAT + f0] = acc1[r] + b;
        }
      }
    }

    if (t < TWARM + TSTEP) {
      // per-XCD step barrier (Round-3 protocol): __syncthreads drains vmcnt,
      // then Nx arrivals on xline[2], last arriver releases xline[3]=t+1.
      __syncthreads();
      if (tid == 0) {
        uint32_t o = __hip_atomic_fetch_add(&xline[2], 1u,
                                            __ATOMIC_RELAXED, __HIP_MEMORY_SCOPE_AGENT);
        if (o == (uint32_t)((t + 1) * Nx - 1))
          __hip_atomic_store(&xline[3], (uint32_t)(t + 1),
                             __ATOMIC_RELAXED, __HIP_MEMORY_SCOPE_AGENT);
        while (__hip_atomic_load(&xline[3], __ATOMIC_RELAXED,
                                 __HIP_MEMORY_SCOPE_AGENT) < (uint32_t)(t + 1))
          __builtin_amdgcn_s_sleep(2);
      }
      __syncthreads();
      v4i ts = srd_cur; srd_cur = srd_nxt; srd_nxt = ts;
      hw = (hw == h1) ? h0 : h1;
    }
  }
}

// ---------------------------------------------------------------------------
extern "C" void kernel_launch(void* const* d_in, const int* in_sizes, int n_in,
                              void* d_out, int out_size, void* d_ws, size_t ws_size,
                              hipStream_t stream) {
  const float* X   = (const float*)d_in[0];  // [256][128][1024]
  const float* Wih = (const float*)d_in[1];  // [2048][1024]
  const float* bih = (const float*)d_in[2];
  const float* Whh = (const float*)d_in[3];  // [2048][2048]
  const float* bhh = (const float*)d_in[4];
  const float* Wfc = (const float*)d_in[5];  // [1024][2048]
  const float* bfc = (const float*)d_in[6];
  float* out = (float*)d_out;

  // ws layout (bytes), ~31.5 MB (Round-3 layout)
  char* ws = (char*)d_ws;
  uint32_t* bar    = (uint32_t*)(ws + 0);          // 4096 B counters
  uint16_t* h0     = (uint16_t*)(ws + 4096);
  uint16_t* h1     = (uint16_t*)(ws + 4096 + 1048576);
  uint16_t* whh_p  = (uint16_t*)(ws + 2101248);
  uint16_t* wih_p  = (uint16_t*)(ws + 10489856);
  uint16_t* wfc_p  = (uint16_t*)(ws + 14684160);
  uint16_t* wfcT_p = (uint16_t*)(ws + 18878464);   // setup only
  uint16_t* comb_p = (uint16_t*)(ws + 23072768);
  float*    b_comb = (float*)(ws + 31461376);
  float*    b_warm = (float*)(ws + 31469568);

  hipMemsetAsync(bar, 0, 4096, stream);

  pack_b<<<(HID*HID/8)/256, 256, 0, stream>>>(Whh, (uint32_t*)whh_p, HID,  HID*HID/8);
  pack_b<<<(HID*FEAT/8)/256, 256, 0, stream>>>(Wih, (uint32_t*)wih_p, FEAT, HID*FEAT/8);
  pack_b<<<(FEAT*HID/8)/256, 256, 0, stream>>>(Wfc, (uint32_t*)wfc_p, HID,  FEAT*HID/8);
  pack_bT<<<(FEAT*HID/8)/256, 256, 0, stream>>>(Wfc, wfcT_p);
  bias_comb_k<<<256, 512, 0, stream>>>(Wih, bih, bhh, bfc, b_comb, b_warm);
  comb_gemm<<<1024, 512, 0, stream>>>(wih_p, wfcT_p, Whh, comb_p);

  rnn_persistent<<<NBLK, NTHR, 0, stream>>>(X, whh_p, wih_p, wfc_p, comb_p,
                                            b_comb, b_warm, bfc, h0, h1, out, bar);
}